// Round 2
// baseline (371.909 us; speedup 1.0000x reference)
//
#include <hip/hip_runtime.h>
#include <math.h>

#define B_ 64
#define S_ 512
#define N_ 24
#define H_ 768
#define C_ 6

// One block per (batch b, segment j): grid (N_, B_), 256 threads = 4 waves.
// Segment j covers tokens [prev+1, end] (prev = -1 for j==0). Each lane owns a
// 12-float H-chunk of W in registers (pinned); wave w processes tokens
// start+w, start+w+4, ... (wave-uniform guards, no divergence). Per-lane
// partials reduce via 64-lane butterfly, cross-wave via 96 B of LDS, thread c
// applies mean + bias + sigmoid and writes out[b][j][c] directly.
// No workspace, no atomics, no second kernel.
__global__ __launch_bounds__(256, 4) void seg_kernel(
    const float* __restrict__ lhs, const int* __restrict__ st,
    const float* __restrict__ W, const float* __restrict__ bias,
    float* __restrict__ out) {
  const int j = blockIdx.x;
  const int b = blockIdx.y;
  const int tid = threadIdx.x;
  const int lane = tid & 63;
  const int wave = tid >> 6;

  const int end = st[b * N_ + j];
  const int prev = (j == 0) ? -1 : st[b * N_ + j - 1];
  float* o = out + ((size_t)b * N_ + j) * C_;

  if (end > 500) {  // block-uniform override: constant vector, skip all reads
    if (tid < C_) {
      const int c = tid;
      const float cl = (c < 3) ? 0.1f : (c == 3 ? 0.3f : (c == 4 ? 0.8f : 0.01f));
      const float cm = (c < 3) ? 0.1f : (c == 3 ? 0.8f : (c == 4 ? 0.3f : 0.01f));
      o[c] = (j == N_ - 1) ? cl : cm;
    }
    return;
  }

  __shared__ float sacc[4][C_];

  // W fragment: lane holds W[c][k*256 + lane*4 .. +3], k=0..2, c=0..5 (72 VGPRs)
  const float4* W4 = (const float4*)W;
  float4 w[3][C_];
#pragma unroll
  for (int k = 0; k < 3; ++k)
#pragma unroll
    for (int c = 0; c < C_; ++c)
      w[k][c] = W4[c * (H_ / 4) + k * 64 + lane];
  // pin: forbid rematerialization of the W loads
#pragma unroll
  for (int k = 0; k < 3; ++k)
    asm volatile("" : "+v"(w[k][0].x), "+v"(w[k][0].y), "+v"(w[k][0].z), "+v"(w[k][0].w),
                       "+v"(w[k][1].x), "+v"(w[k][1].y), "+v"(w[k][1].z), "+v"(w[k][1].w),
                       "+v"(w[k][2].x), "+v"(w[k][2].y), "+v"(w[k][2].z), "+v"(w[k][2].w),
                       "+v"(w[k][3].x), "+v"(w[k][3].y), "+v"(w[k][3].z), "+v"(w[k][3].w),
                       "+v"(w[k][4].x), "+v"(w[k][4].y), "+v"(w[k][4].z), "+v"(w[k][4].w),
                       "+v"(w[k][5].x), "+v"(w[k][5].y), "+v"(w[k][5].z), "+v"(w[k][5].w));

  const int start = prev + 1;
  const int len = end - start + 1;  // >= 1 by construction
  // wave handles tokens start + wave + 4*r, r = 0..nr-1
  const int nr = (len - wave + 3) >> 2;  // len>=1, wave<=3 -> argument >= 1, never negative

  const float4* x4 = (const float4*)(lhs + ((size_t)b * S_ + start + wave) * H_);

  float racc[C_] = {0.f, 0.f, 0.f, 0.f, 0.f, 0.f};
#pragma unroll 1
  for (int r0 = 0; r0 < nr; r0 += 8) {
    // prefetch up to 8 tokens (24 independent 1-KiB wave loads in flight);
    // guards are wave-uniform -> s_cbranch, no lane divergence, no waste reads
    float4 x[8][3];
#pragma unroll
    for (int t = 0; t < 8; ++t) {
      if (r0 + t < nr) {
        const int off = (r0 + t) * 768;  // 4 tokens * 192 float4
        x[t][0] = x4[off + lane];
        x[t][1] = x4[off + 64 + lane];
        x[t][2] = x4[off + 128 + lane];
      }
    }
#pragma unroll
    for (int t = 0; t < 8; ++t) {
      if (r0 + t < nr) {
#pragma unroll
        for (int k = 0; k < 3; ++k)
#pragma unroll
          for (int c = 0; c < C_; ++c)
            racc[c] += x[t][k].x * w[k][c].x + x[t][k].y * w[k][c].y +
                       x[t][k].z * w[k][c].z + x[t][k].w * w[k][c].w;
      }
    }
  }

  // 64-lane butterfly reduce per class
#pragma unroll
  for (int c = 0; c < C_; ++c) {
    float v = racc[c];
    v += __shfl_xor(v, 1);
    v += __shfl_xor(v, 2);
    v += __shfl_xor(v, 4);
    v += __shfl_xor(v, 8);
    v += __shfl_xor(v, 16);
    v += __shfl_xor(v, 32);
    racc[c] = v;
  }
  if (lane == 0) {
#pragma unroll
    for (int c = 0; c < C_; ++c) sacc[wave][c] = racc[c];
  }
  __syncthreads();

  if (tid < C_) {
    const float ssum = sacc[0][tid] + sacc[1][tid] + sacc[2][tid] + sacc[3][tid];
    const float logit = ssum / (float)len + bias[tid];
    o[tid] = 1.0f / (1.0f + expf(-logit));
  }
}

extern "C" void kernel_launch(void* const* d_in, const int* in_sizes, int n_in,
                              void* d_out, int out_size, void* d_ws, size_t ws_size,
                              hipStream_t stream) {
  const float* lhs  = (const float*)d_in[0];  // [B,S,H] fp32
  const int*   st   = (const int*)d_in[1];    // [B,N] int32
  const float* W    = (const float*)d_in[2];  // [C,H] fp32
  const float* bias = (const float*)d_in[3];  // [C] fp32

  seg_kernel<<<dim3(N_, B_), 256, 0, stream>>>(lhs, st, W, bias, (float*)d_out);
}

// Round 3
// 184.170 us; speedup vs baseline: 2.0194x; 2.0194x over previous
//
#include <hip/hip_runtime.h>
#include <math.h>

#define B_ 64
#define S_ 512
#define N_ 24
#define H_ 768
#define C_ 6
#define CHUNKS 16                        // blocks per batch
#define TOK_PER_BLOCK (S_ / CHUNKS)      // 32 tokens per block
#define TOK_PER_WAVE (TOK_PER_BLOCK / 4) // 8 contiguous tokens per wave

// One wave handles 8 contiguous tokens. Lane holds an H-chunk of W in regs
// (pinned via asm so the compiler cannot rematerialize the loads), prefetches
// all 24 float4s of token data upfront (24 loads in flight), accumulates a
// per-lane per-segment partial in registers, and flushes to LDS only when the
// (wave-uniform) segment id changes.
// launch_bounds(256,4): 36KB LDS x4 = 144KB/CU, VGPR cap 128 (measured 112
// for this loop in round 1) -> 4 blocks/CU, 1024 blocks = 256CU x 4 exactly.
__global__ __launch_bounds__(256, 4) void seg_proj_kernel(
    const float* __restrict__ lhs, const int* __restrict__ st,
    const float* __restrict__ W, float* __restrict__ outbuf, int use_atomic) {
  __shared__ float acc[N_ * C_ * 64];  // 36 KB
  const int tid = threadIdx.x;
  const int lane = tid & 63;
  const int wave = tid >> 6;
  const int b = blockIdx.x / CHUNKS;
  const int chunk = blockIdx.x % CHUNKS;

  // zero LDS accumulators (2304 float4s / 256 threads = 9 each)
  float4* accv = (float4*)acc;
#pragma unroll
  for (int i = 0; i < 9; ++i)
    accv[i * 256 + tid] = make_float4(0.f, 0.f, 0.f, 0.f);

  // boundaries resident in lanes (sentinel for lanes >= 24)
  int stb_l = (lane < N_) ? st[b * N_ + lane] : 0x7fffffff;
  // tokens s > min(last_boundary, 500) are provably discarded downstream:
  // s > last  -> past the final segment (never flushed);
  // s > 500   -> its segment has end >= s > 500 -> override branch in finalize.
  const int last = __shfl(stb_l, N_ - 1);
  const int lim = last > 500 ? 500 : last;

  // W fragment: lane holds W[c][k*256 + lane*4 .. +3], k=0..2, c=0..5 (72 VGPRs)
  const float4* W4 = (const float4*)W;
  float4 w[3][C_];
#pragma unroll
  for (int k = 0; k < 3; ++k)
#pragma unroll
    for (int c = 0; c < C_; ++c)
      w[k][c] = W4[c * (H_ / 4) + k * 64 + lane];
  // pin: forbid rematerialization of the W loads (24 operands per asm stmt)
#pragma unroll
  for (int k = 0; k < 3; ++k)
    asm volatile("" : "+v"(w[k][0].x), "+v"(w[k][0].y), "+v"(w[k][0].z), "+v"(w[k][0].w),
                       "+v"(w[k][1].x), "+v"(w[k][1].y), "+v"(w[k][1].z), "+v"(w[k][1].w),
                       "+v"(w[k][2].x), "+v"(w[k][2].y), "+v"(w[k][2].z), "+v"(w[k][2].w),
                       "+v"(w[k][3].x), "+v"(w[k][3].y), "+v"(w[k][3].z), "+v"(w[k][3].w),
                       "+v"(w[k][4].x), "+v"(w[k][4].y), "+v"(w[k][4].z), "+v"(w[k][4].w),
                       "+v"(w[k][5].x), "+v"(w[k][5].y), "+v"(w[k][5].z), "+v"(w[k][5].w));

  __syncthreads();

  const int s_base = chunk * TOK_PER_BLOCK + wave * TOK_PER_WAVE;
  // wave-uniform skip: this wave's 8 tokens are all discarded downstream
  if (s_base <= lim) {
    // prefetch all 8 tokens (24 independent 1-KiB wave loads in flight)
    const float4* x4 = (const float4*)(lhs + ((size_t)b * S_ + s_base) * H_);
    float4 x[TOK_PER_WAVE][3];
#pragma unroll
    for (int t = 0; t < TOK_PER_WAVE; ++t) {
      x[t][0] = x4[t * 192 + lane];
      x[t][1] = x4[t * 192 + 64 + lane];
      x[t][2] = x4[t * 192 + 128 + lane];
    }

    float racc[C_] = {0.f, 0.f, 0.f, 0.f, 0.f, 0.f};
    int cur_seg = N_;  // sentinel: nothing pending
#pragma unroll
    for (int t = 0; t < TOK_PER_WAVE; ++t) {
      const int s = s_base + t;
      // segment id = count of boundaries < s (wave-uniform)
      const int seg = (int)__popcll(__ballot(stb_l < s));
      if (seg != cur_seg) {  // rare: ~1.4 times per wave
        if (cur_seg < N_) {
#pragma unroll
        for (int c = 0; c < C_; ++c)
          atomicAdd(&acc[(cur_seg * C_ + c) * 64 + lane], racc[c]);
        }
#pragma unroll
        for (int c = 0; c < C_; ++c) racc[c] = 0.f;
        cur_seg = seg;
      }
      // tokens past the last boundary have seg==24; they accumulate into racc
      // but cur_seg==24 is never flushed, so they are ignored.
#pragma unroll
      for (int k = 0; k < 3; ++k)
#pragma unroll
        for (int c = 0; c < C_; ++c)
          racc[c] += x[t][k].x * w[k][c].x + x[t][k].y * w[k][c].y +
                     x[t][k].z * w[k][c].z + x[t][k].w * w[k][c].w;
    }
    if (cur_seg < N_) {
#pragma unroll
      for (int c = 0; c < C_; ++c)
        atomicAdd(&acc[(cur_seg * C_ + c) * 64 + lane], racc[c]);
    }
  }

  __syncthreads();
  // block reduce: 144 threads each sum 64 lane-partials (skewed: conflict-free)
  if (tid < N_ * C_) {
    float v = 0.f;
    const int base = tid * 64;
#pragma unroll 8
    for (int i = 0; i < 64; ++i) v += acc[base + ((i + tid) & 63)];
    if (use_atomic)
      atomicAdd(&outbuf[b * N_ * C_ + tid], v);
    else
      outbuf[(size_t)blockIdx.x * (N_ * C_) + tid] = v;
  }
}

__global__ __launch_bounds__(256) void finalize_kernel(
    const float* __restrict__ buf, const int* __restrict__ st,
    const float* __restrict__ bias, float* __restrict__ out, int use_atomic) {
  int idx = blockIdx.x * blockDim.x + threadIdx.x;
  if (idx >= B_ * N_ * C_) return;
  int c = idx % C_;
  int j = (idx / C_) % N_;
  int b = idx / (N_ * C_);
  float ssum;
  if (use_atomic) {
    ssum = buf[idx];
  } else {
    ssum = 0.f;
#pragma unroll
    for (int k = 0; k < CHUNKS; ++k)
      ssum += buf[(size_t)(b * CHUNKS + k) * (N_ * C_) + j * C_ + c];
  }
  int end = st[b * N_ + j];
  int prev = (j == 0) ? -1 : st[b * N_ + j - 1];
  float len = (float)(end - prev);
  float logit = ssum / len + bias[c];
  float p = 1.0f / (1.0f + expf(-logit));
  if (end > 500) {
    float cl = (c < 3) ? 0.1f : (c == 3 ? 0.3f : (c == 4 ? 0.8f : 0.01f));
    float cm = (c < 3) ? 0.1f : (c == 3 ? 0.8f : (c == 4 ? 0.3f : 0.01f));
    p = (j == N_ - 1) ? cl : cm;
  }
  out[idx] = p;
}

extern "C" void kernel_launch(void* const* d_in, const int* in_sizes, int n_in,
                              void* d_out, int out_size, void* d_ws, size_t ws_size,
                              hipStream_t stream) {
  const float* lhs  = (const float*)d_in[0];  // [B,S,H] fp32
  const int*   st   = (const int*)d_in[1];    // [B,N] int32
  const float* W    = (const float*)d_in[2];  // [C,H] fp32
  const float* bias = (const float*)d_in[3];  // [C] fp32

  const size_t need = (size_t)B_ * CHUNKS * N_ * C_ * sizeof(float);  // 576 KB
  const int use_atomic = (ws_size < need) ? 1 : 0;
  if (use_atomic)
    hipMemsetAsync(d_ws, 0, (size_t)B_ * N_ * C_ * sizeof(float), stream);

  seg_proj_kernel<<<B_ * CHUNKS, 256, 0, stream>>>(lhs, st, W, (float*)d_ws, use_atomic);
  finalize_kernel<<<(B_ * N_ * C_ + 255) / 256, 256, 0, stream>>>(
      (float*)d_ws, st, bias, (float*)d_out, use_atomic);
}

// Round 4
// 152.681 us; speedup vs baseline: 2.4359x; 1.2062x over previous
//
#include <hip/hip_runtime.h>
#include <math.h>

#define B_ 64
#define S_ 512
#define N_ 24
#define H_ 768
#define C_ 6
#define CHUNKS 8                         // blocks per batch
#define TOK_PER_BLOCK (S_ / CHUNKS)      // 64 tokens per block
#define TOK_PER_WAVE (TOK_PER_BLOCK / 4) // 16 tokens per wave (two 8-token halves)
#define NC (N_ * C_)                     // 144

// Arrival counters for the last-block-per-batch finalize. Zero-initialized at
// module load; the finalizing block re-arms its counter to 0 every launch, so
// the protocol survives graph replay. Lives in __device__ memory: the harness's
// workspace poison cannot touch it.
__device__ int g_cnt[B_];

// One fused dispatch. Per block: stream 64 tokens (proven 112-VGPR inner loop:
// register-pinned W fragment, 24-deep float4 prefetch per 8-token half,
// ballot segment-id, LDS lane-partial accumulators), reduce to 144 partials,
// publish them to ws with device-scope atomicExch (cross-XCD coherent), then
// atomically count arrivals; the 8th block of each batch reads the 8 partial
// vectors back with coherent atomicAdd(p,0) reads and finalizes in place.
// DO NOT raise the occupancy bound: this loop needs ~112 VGPRs; any cap below
// that (e.g. __launch_bounds__(256,4) -> 64 VGPRs) spills x[8][3] to scratch
// (round 2: 290us, round 3: 75us vs ~20us clean).
__global__ __launch_bounds__(256, 2) void seg_proj_fused(
    const float* __restrict__ lhs, const int* __restrict__ st,
    const float* __restrict__ W, const float* __restrict__ bias,
    float* __restrict__ ws, float* __restrict__ out) {
  __shared__ float acc[NC * 64];  // 36 KB
  __shared__ int s_old;
  const int tid = threadIdx.x;
  const int lane = tid & 63;
  const int wave = tid >> 6;
  const int b = blockIdx.x >> 3;       // CHUNKS == 8
  const int chunk = blockIdx.x & 7;

  // zero LDS accumulators (2304 float4s / 256 threads = 9 each)
  float4* accv = (float4*)acc;
#pragma unroll
  for (int i = 0; i < 9; ++i)
    accv[i * 256 + tid] = make_float4(0.f, 0.f, 0.f, 0.f);

  // boundaries resident in lanes (sentinel for lanes >= 24)
  int stb_l = (lane < N_) ? st[b * N_ + lane] : 0x7fffffff;
  // tokens s > min(last_boundary, 500) are provably discarded downstream:
  //   s > last -> past the final segment (never flushed);
  //   s > 500  -> its segment has end >= s > 500 -> override in finalize.
  // Non-overridden segments have end <= min(last,500), so every token they
  // need satisfies s <= lim and its half-tile is never skipped.
  const int last = __shfl(stb_l, N_ - 1);
  const int lim = last > 500 ? 500 : last;

  // W fragment: lane holds W[c][k*256 + lane*4 .. +3], k=0..2, c=0..5 (72 VGPRs)
  const float4* W4 = (const float4*)W;
  float4 w[3][C_];
#pragma unroll
  for (int k = 0; k < 3; ++k)
#pragma unroll
    for (int c = 0; c < C_; ++c)
      w[k][c] = W4[c * (H_ / 4) + k * 64 + lane];
  // pin: forbid rematerialization of the W loads
#pragma unroll
  for (int k = 0; k < 3; ++k)
    asm volatile("" : "+v"(w[k][0].x), "+v"(w[k][0].y), "+v"(w[k][0].z), "+v"(w[k][0].w),
                       "+v"(w[k][1].x), "+v"(w[k][1].y), "+v"(w[k][1].z), "+v"(w[k][1].w),
                       "+v"(w[k][2].x), "+v"(w[k][2].y), "+v"(w[k][2].z), "+v"(w[k][2].w),
                       "+v"(w[k][3].x), "+v"(w[k][3].y), "+v"(w[k][3].z), "+v"(w[k][3].w),
                       "+v"(w[k][4].x), "+v"(w[k][4].y), "+v"(w[k][4].z), "+v"(w[k][4].w),
                       "+v"(w[k][5].x), "+v"(w[k][5].y), "+v"(w[k][5].z), "+v"(w[k][5].w));

  __syncthreads();

  const int s_base = chunk * TOK_PER_BLOCK + wave * TOK_PER_WAVE;
  const float4* x4 = (const float4*)(lhs + ((size_t)b * S_ + s_base) * H_);

  float racc[C_] = {0.f, 0.f, 0.f, 0.f, 0.f, 0.f};
  int cur_seg = N_;  // sentinel: nothing pending
#pragma unroll 1     // do NOT unroll: x[8][3] + w[3][6] must fit under 256 VGPRs
  for (int h = 0; h < 2; ++h) {
    const int hb = s_base + h * 8;
    if (hb <= lim) {  // wave-uniform skip of provably-discarded 8-token halves
      // prefetch 8 tokens (24 independent 1-KiB wave loads in flight)
      float4 x[8][3];
#pragma unroll
      for (int t = 0; t < 8; ++t) {
        const int tt = h * 8 + t;
        x[t][0] = x4[tt * 192 + lane];
        x[t][1] = x4[tt * 192 + 64 + lane];
        x[t][2] = x4[tt * 192 + 128 + lane];
      }
#pragma unroll
      for (int t = 0; t < 8; ++t) {
        const int s = hb + t;
        // segment id = count of boundaries < s (wave-uniform)
        const int seg = (int)__popcll(__ballot(stb_l < s));
        if (seg != cur_seg) {  // rare: ~1-2 times per wave
          if (cur_seg < N_) {
#pragma unroll
            for (int c = 0; c < C_; ++c)
              atomicAdd(&acc[(cur_seg * C_ + c) * 64 + lane], racc[c]);
          }
#pragma unroll
          for (int c = 0; c < C_; ++c) racc[c] = 0.f;
          cur_seg = seg;
        }
        // tokens past the last boundary have seg==24; never flushed -> ignored
#pragma unroll
        for (int k = 0; k < 3; ++k)
#pragma unroll
          for (int c = 0; c < C_; ++c)
            racc[c] += x[t][k].x * w[k][c].x + x[t][k].y * w[k][c].y +
                       x[t][k].z * w[k][c].z + x[t][k].w * w[k][c].w;
      }
    }
  }
  if (cur_seg < N_) {
#pragma unroll
    for (int c = 0; c < C_; ++c)
      atomicAdd(&acc[(cur_seg * C_ + c) * 64 + lane], racc[c]);
  }

  __syncthreads();

  // block reduce: 144 threads each sum 64 lane-partials (skewed: conflict-free),
  // publish with device-scope atomicExch (coherent point, cross-XCD safe)
  if (tid < NC) {
    float v = 0.f;
    const int base = tid * 64;
#pragma unroll 8
    for (int i = 0; i < 64; ++i) v += acc[base + ((i + tid) & 63)];
    atomicExch(&ws[(size_t)blockIdx.x * NC + tid], v);
  }

  __syncthreads();  // drains vmcnt: all 144 atomicExch are at the coherent point
  if (tid == 0) s_old = atomicAdd(&g_cnt[b], 1);
  __syncthreads();

  if (s_old == CHUNKS - 1) {  // this block is the last arrival for batch b
    if (tid < NC) {
      float* base = ws + (size_t)b * CHUNKS * NC + tid;
      float ssum = 0.f;
#pragma unroll
      for (int k = 0; k < CHUNKS; ++k)
        ssum += atomicAdd(&base[k * NC], 0.0f);  // coherent RMW reads
      const int c = tid % C_;
      const int j = tid / C_;
      const int end = st[b * N_ + j];
      const int prev = (j == 0) ? -1 : st[b * N_ + j - 1];
      const float logit = ssum / (float)(end - prev) + bias[c];
      float p = 1.0f / (1.0f + expf(-logit));
      if (end > 500) {
        const float cl = (c < 3) ? 0.1f : (c == 3 ? 0.3f : (c == 4 ? 0.8f : 0.01f));
        const float cm = (c < 3) ? 0.1f : (c == 3 ? 0.8f : (c == 4 ? 0.3f : 0.01f));
        p = (j == N_ - 1) ? cl : cm;
      }
      out[b * NC + tid] = p;
    }
    if (tid == 0) atomicExch(&g_cnt[b], 0);  // re-arm for the next launch
  }
}

extern "C" void kernel_launch(void* const* d_in, const int* in_sizes, int n_in,
                              void* d_out, int out_size, void* d_ws, size_t ws_size,
                              hipStream_t stream) {
  const float* lhs  = (const float*)d_in[0];  // [B,S,H] fp32
  const int*   st   = (const int*)d_in[1];    // [B,N] int32
  const float* W    = (const float*)d_in[2];  // [C,H] fp32
  const float* bias = (const float*)d_in[3];  // [C] fp32

  // needs B_*CHUNKS*NC*4 = 294912 B of workspace for partials
  seg_proj_fused<<<B_ * CHUNKS, 256, 0, stream>>>(
      lhs, st, W, bias, (float*)d_ws, (float*)d_out);
}